// Round 14
// baseline (544.454 us; speedup 1.0000x reference)
//
#include <hip/hip_runtime.h>
#include <hip/hip_bf16.h>
#include <math.h>

// ---------------------------------------------------------------------------
// TransformerEncoder L=3,B=2,S=2048,D=1024,H=16,Dh=64,DF=4096.
// Round 14: attn split-KV=2 (grid z, unnormalized partials + lsum, tiny
// combine kernel) + merged per-wave P buffer -> 37.9KB LDS -> 4 blocks/CU.
// FF1 8-phase, other GEMMs and glue unchanged from r13.
// ---------------------------------------------------------------------------

#define DEVINL __device__ __forceinline__
typedef unsigned short ushort_t;
using short8 = __attribute__((ext_vector_type(8))) short;
using f32x4  = __attribute__((ext_vector_type(4))) float;

#if defined(__has_builtin)
#if __has_builtin(__builtin_amdgcn_exp2f)
#define EXPFN(x) __builtin_amdgcn_exp2f(x)
#define QSCALE 0.18033688011112042f  // 0.125 * log2(e)
#define HAVE_EXP2 1
#endif
#endif
#ifndef HAVE_EXP2
#define EXPFN(x) __expf(x)
#define QSCALE 0.125f
#endif

DEVINL short f2b(float f) {  // fp32 -> bf16 bits, RNE
  unsigned u = __float_as_uint(f);
  u += 0x7fff + ((u >> 16) & 1);
  return (short)(u >> 16);
}
DEVINL unsigned pk2(float a, float b) {  // two fp32 -> packed bf16x2
  unsigned ua = __float_as_uint(a), ub = __float_as_uint(b);
  ua += 0x7fff + ((ua >> 16) & 1);
  ub += 0x7fff + ((ub >> 16) & 1);
  return (ua >> 16) | (ub & 0xffff0000u);
}
DEVINL unsigned pkc(float a, float b) {  // packed cvt (v_cvt_pk_bf16_f32)
  float2 f; f.x = a; f.y = b;
  __hip_bfloat162 h = __float22bfloat162_rn(f);
  return *reinterpret_cast<unsigned*>(&h);
}
DEVINL float bl(unsigned u) { return __uint_as_float(u << 16); }
DEVINL float bh(unsigned u) { return __uint_as_float(u & 0xffff0000u); }
DEVINL f32x4 mfma16(short8 a, short8 b, f32x4 c) {
  return __builtin_amdgcn_mfma_f32_16x16x32_bf16(a, b, c, 0, 0, 0);
}

typedef __attribute__((address_space(3))) void lds_void;
typedef __attribute__((address_space(1))) void gbl_void;
DEVINL void gl16(const void* g, void* l) {
  __builtin_amdgcn_global_load_lds((const gbl_void*)(unsigned long long)g,
                                   (lds_void*)(unsigned long long)l, 16, 0, 0);
}
template <int N> DEVINL void waitvm() {
  asm volatile("s_waitcnt vmcnt(%0)" ::"n"(N) : "memory");
}
DEVINL void barrier_raw() { __builtin_amdgcn_s_barrier(); }
DEVINL void sched0() { __builtin_amdgcn_sched_barrier(0); }
DEVINL void waitlgkm0() {
  asm volatile("s_waitcnt lgkmcnt(0)" ::: "memory");
}

// --------------------------- fp32 -> bf16 convert ---------------------------
__global__ __launch_bounds__(256)
void conv_bf16(const float* __restrict__ src, ushort_t* __restrict__ dst,
               int n8) {
  int i = blockIdx.x * 256 + threadIdx.x;
  const int stride = gridDim.x * 256;
  for (; i < n8; i += stride) {
    float4 a = ((const float4*)src)[2 * i];
    float4 b = ((const float4*)src)[2 * i + 1];
    uint4 o;
    o.x = pk2(a.x, a.y); o.y = pk2(a.z, a.w);
    o.z = pk2(b.x, b.y); o.w = pk2(b.z, b.w);
    ((uint4*)dst)[i] = o;
  }
}

// -------- LayerNorm of (pa + pb + bias + R) — bf16 in, bf16(+fp32) out ------
DEVINL float block_sum(float v, float* red) {
#pragma unroll
  for (int off = 32; off > 0; off >>= 1) v += __shfl_xor(v, off, 64);
  if ((threadIdx.x & 63) == 0) red[threadIdx.x >> 6] = v;
  __syncthreads();
  float r = red[0] + red[1] + red[2] + red[3];
  __syncthreads();
  return r;
}

template <bool WF>
__global__ __launch_bounds__(256)
void ln_fuse(const ushort_t* __restrict__ pa, const ushort_t* __restrict__ pb,
             const float* __restrict__ bias, const ushort_t* __restrict__ Rb,
             const float* __restrict__ g, const float* __restrict__ b,
             ushort_t* __restrict__ outb, float* __restrict__ outf) {
  __shared__ float red[4];
  const size_t base = (size_t)blockIdx.x * 1024 + threadIdx.x * 4;
  uint2 ua = *(const uint2*)(pa + base);
  uint2 ub = *(const uint2*)(pb + base);
  uint2 ur = *(const uint2*)(Rb + base);
  float4 vbi = *(const float4*)(bias + threadIdx.x * 4);
  float4 v;
  v.x = bl(ua.x) + bl(ub.x) + bl(ur.x) + vbi.x;
  v.y = bh(ua.x) + bh(ub.x) + bh(ur.x) + vbi.y;
  v.z = bl(ua.y) + bl(ub.y) + bl(ur.y) + vbi.z;
  v.w = bh(ua.y) + bh(ub.y) + bh(ur.y) + vbi.w;
  float s = block_sum(v.x + v.y + v.z + v.w, red);
  float mean = s * (1.0f / 1024.0f);
  float dx = v.x - mean, dy = v.y - mean, dz = v.z - mean, dw = v.w - mean;
  float sq = block_sum(dx * dx + dy * dy + dz * dz + dw * dw, red);
  float rstd = rsqrtf(sq * (1.0f / 1024.0f) + 1e-5f);
  const float4 gv = *(const float4*)(g + threadIdx.x * 4);
  const float4 bv = *(const float4*)(b + threadIdx.x * 4);
  float4 o;
  o.x = dx * rstd * gv.x + bv.x;
  o.y = dy * rstd * gv.y + bv.y;
  o.z = dz * rstd * gv.z + bv.z;
  o.w = dw * rstd * gv.w + bv.w;
  uint2 p;
  p.x = pk2(o.x, o.y); p.y = pk2(o.z, o.w);
  *(uint2*)(outb + base) = p;
  if (WF) *(float4*)(outf + base) = o;
}

// ------------------ MFMA GEMM (dbuf + counted vmcnt + raw barriers) ---------
// C[M,N] = A[M,K] @ W[N,K]^T (+bias)(+relu). split-K via blockIdx.z writes
// bf16 partials at offset z*M*N (OBF). EPI: 1=bias 4=relu.
template <int BM, int BN, int WR, int WC, bool OBF, int EPI, bool SWZ>
__global__ __launch_bounds__(WR * WC * 64)
void gemm_db(const ushort_t* __restrict__ A, const ushort_t* __restrict__ W,
             const float* __restrict__ bias, void* __restrict__ Cp, int M,
             int N, int Klen, int lda, int ldw) {
  constexpr int THREADS = WR * WC * 64;
  constexpr int FM = BM / WR / 16;
  constexpr int FN = BN / WC / 16;
  constexpr int CA = BM * 8 / THREADS;
  constexpr int CB = BN * 8 / THREADS;
  constexpr int L = CA + CB;
  __shared__ __align__(16) ushort_t As[2][BM * 64];
  __shared__ __align__(16) ushort_t Bs[2][BN * 64];
  const int tid = threadIdx.x;
  const int lane = tid & 63, lo = lane & 15, hi = lane >> 4, w = tid >> 6;
  int bx = blockIdx.x, by = blockIdx.y;
  if (SWZ) {
    int id = by * gridDim.x + bx;
    const int cpx = (gridDim.x * gridDim.y) >> 3;
    id = (id & 7) * cpx + (id >> 3);
    bx = id % gridDim.x;
    by = id / gridDim.x;
  }
  const int m0 = by * BM, n0 = bx * BN;
  const int wm = (w / WC) * (BM / WR), wn = (w % WC) * (BN / WC);
  const int kbase = blockIdx.z * Klen;

  auto stage = [&](int t, int buf) {
    const int k0 = kbase + t * 64;
#pragma unroll
    for (int i = 0; i < CA; ++i) {
      const int c = i * THREADS + tid;
      const int r = c >> 3, sg = (c & 7) ^ (r & 7);
      gl16(A + (size_t)(m0 + r) * lda + k0 + sg * 8, &As[buf][c * 8]);
    }
#pragma unroll
    for (int i = 0; i < CB; ++i) {
      const int c = i * THREADS + tid;
      const int r = c >> 3, sg = (c & 7) ^ (r & 7);
      gl16(W + (size_t)(n0 + r) * ldw + k0 + sg * 8, &Bs[buf][c * 8]);
    }
  };

  f32x4 acc[FM][FN] = {};
  auto compute = [&](int cur) {
#pragma unroll
    for (int ks = 0; ks < 2; ++ks) {
      short8 af[FM], bf_[FN];
#pragma unroll
      for (int fm = 0; fm < FM; ++fm) {
        const int row = wm + fm * 16 + lo;
        af[fm] = *(const short8*)
            &As[cur][row * 64 + (((ks * 4 + hi) ^ (row & 7)) << 3)];
      }
#pragma unroll
      for (int fn = 0; fn < FN; ++fn) {
        const int row = wn + fn * 16 + lo;
        bf_[fn] = *(const short8*)
            &Bs[cur][row * 64 + (((ks * 4 + hi) ^ (row & 7)) << 3)];
      }
#pragma unroll
      for (int fm = 0; fm < FM; ++fm)
#pragma unroll
        for (int fn = 0; fn < FN; ++fn)
          acc[fm][fn] = mfma16(af[fm], bf_[fn], acc[fm][fn]);
    }
  };

  const int nt = Klen / 64;
  stage(0, 0);
  for (int t = 0; t < nt - 1; ++t) {
    const int cur = t & 1;
    stage(t + 1, cur ^ 1);   // loads stay in flight across both barriers
    waitvm<L>();             // own stage(t) complete (oldest-first retire)
    barrier_raw(); sched0(); // all waves: tile t resident
    compute(cur);
    barrier_raw(); sched0(); // all waves done reading buf cur before restage
  }
  waitvm<0>();
  barrier_raw(); sched0();
  compute((nt - 1) & 1);

  float bv[FN];
#pragma unroll
  for (int fn = 0; fn < FN; ++fn)
    bv[fn] = (EPI & 1) ? bias[n0 + wn + fn * 16 + lo] : 0.f;
#pragma unroll
  for (int fm = 0; fm < FM; ++fm)
#pragma unroll
    for (int fn = 0; fn < FN; ++fn) {
      const int col = n0 + wn + fn * 16 + lo;
#pragma unroll
      for (int r = 0; r < 4; ++r) {
        const int row = m0 + wm + fm * 16 + hi * 4 + r;
        float v = acc[fm][fn][r] + bv[fn];
        if (EPI & 4) v = fmaxf(v, 0.f);
        if (OBF) {
          ushort_t* Cb = (ushort_t*)Cp + (size_t)blockIdx.z * M * N;
          Cb[(size_t)row * N + col] = (ushort_t)f2b(v);
        } else {
          float* Cf = (float*)Cp + (size_t)blockIdx.z * M * N;
          Cf[(size_t)row * N + col] = v;
        }
      }
    }
}

// ---------------- 8-phase 256^2 GEMM (T2+T3+T4+T5, m201 template) -----------
template <int EPI, bool SWZ>
__global__ __launch_bounds__(512, 2)
void gemm_8p(const ushort_t* __restrict__ A, const ushort_t* __restrict__ W,
             const float* __restrict__ bias, ushort_t* __restrict__ Cp, int M,
             int N, int K, int lda, int ldw) {
  __shared__ __align__(16) ushort_t As[2][256 * 64];
  __shared__ __align__(16) ushort_t Bs[2][256 * 64];
  const int tid = threadIdx.x;
  const int lane = tid & 63, lo = lane & 15, hi = lane >> 4, w = tid >> 6;
  const int wr = w >> 2, wc = w & 3;
  int bx = blockIdx.x, by = blockIdx.y;
  if (SWZ) {
    int id = by * gridDim.x + bx;
    const int cpx = (gridDim.x * gridDim.y) >> 3;
    id = (id & 7) * cpx + (id >> 3);
    bx = id % gridDim.x;
    by = id / gridDim.x;
  }
  const int m0 = by * 256, n0 = bx * 256;
  const int wm = wr * 128, wn = wc * 64;

  const int c0 = tid, c1 = 512 + tid;
  const int r0 = c0 >> 3, g0 = ((c0 & 7) ^ (r0 & 7)) << 3;
  const int r1 = c1 >> 3, g1 = ((c1 & 7) ^ (r1 & 7)) << 3;

  auto stA = [&](int tile, int half, int buf) {
    const ushort_t* s = A + (size_t)(m0 + half * 128) * lda + tile * 64;
    ushort_t* d = &As[buf][half * 128 * 64];
    gl16(s + (size_t)r0 * lda + g0, d + c0 * 8);
    gl16(s + (size_t)r1 * lda + g1, d + c1 * 8);
  };
  auto stB = [&](int tile, int half, int buf) {
    const ushort_t* s = W + (size_t)(n0 + half * 128) * ldw + tile * 64;
    ushort_t* d = &Bs[buf][half * 128 * 64];
    gl16(s + (size_t)r0 * ldw + g0, d + c0 * 8);
    gl16(s + (size_t)r1 * ldw + g1, d + c1 * 8);
  };

  f32x4 acc[8][4] = {};
  short8 af[2][4], bfA[2][2], bfB[2][2];

  auto ldA = [&](int buf, int qr) {
#pragma unroll
    for (int ks = 0; ks < 2; ++ks)
#pragma unroll
      for (int fm = 0; fm < 4; ++fm) {
        const int row = wm + qr * 64 + fm * 16 + lo;
        af[ks][fm] = *(const short8*)
            &As[buf][row * 64 + (((ks * 4 + hi) ^ (row & 7)) << 3)];
      }
  };
  auto ldB = [&](int buf, int qc, short8 (&bf)[2][2]) {
#pragma unroll
    for (int ks = 0; ks < 2; ++ks)
#pragma unroll
      for (int fn = 0; fn < 2; ++fn) {
        const int row = wn + qc * 32 + fn * 16 + lo;
        bf[ks][fn] = *(const short8*)
            &Bs[buf][row * 64 + (((ks * 4 + hi) ^ (row & 7)) << 3)];
      }
  };
  auto mmaQ = [&](auto qr, auto qc, short8 (&bf)[2][2]) {
    constexpr int QR = decltype(qr)::value, QC = decltype(qc)::value;
    __builtin_amdgcn_s_setprio(1);
#pragma unroll
    for (int ks = 0; ks < 2; ++ks)
#pragma unroll
      for (int fm = 0; fm < 4; ++fm)
#pragma unroll
        for (int fn = 0; fn < 2; ++fn)
          acc[QR * 4 + fm][QC * 2 + fn] = mfma16(
              af[ks][fm], bf[ks][fn], acc[QR * 4 + fm][QC * 2 + fn]);
    __builtin_amdgcn_s_setprio(0);
  };
  using I0 = std::integral_constant<int, 0>;
  using I1 = std::integral_constant<int, 1>;

  const int nt = K / 64;
  const int ni = nt / 2;

  stA(0, 0, 0); stA(0, 1, 0); stB(0, 0, 0); stB(0, 1, 0);
  stB(1, 0, 1); stB(1, 1, 1);
  waitvm<4>();
  barrier_raw();

  for (int j = 0; j < ni; ++j) {
    const int t1 = 2 * j + 1, t2 = 2 * j + 2, t3 = 2 * j + 3;
    const bool s2 = t2 < nt, s3 = t3 < nt;
    const bool last = (j == ni - 1);
    ldA(0, 0); ldB(0, 0, bfA);
    stA(t1, 0, 1);
    barrier_raw(); waitlgkm0(); sched0();
    mmaQ(I0{}, I0{}, bfA);
    barrier_raw();
    ldB(0, 1, bfB);
    stA(t1, 1, 1);
    barrier_raw(); waitlgkm0(); sched0();
    mmaQ(I0{}, I1{}, bfB);
    barrier_raw();
    ldA(0, 1);
    if (s2) stB(t2, 0, 0);
    barrier_raw(); waitlgkm0(); sched0();
    mmaQ(I1{}, I1{}, bfB);
    barrier_raw();
    if (s2) stB(t2, 1, 0);
    if (last) waitvm<0>(); else waitvm<4>();
    barrier_raw();
    mmaQ(I1{}, I0{}, bfA);
    barrier_raw();
    ldA(1, 0); ldB(1, 0, bfA);
    if (s2) stA(t2, 0, 0);
    barrier_raw(); waitlgkm0(); sched0();
    mmaQ(I0{}, I0{}, bfA);
    barrier_raw();
    ldB(1, 1, bfB);
    if (s2) stA(t2, 1, 0);
    barrier_raw(); waitlgkm0(); sched0();
    mmaQ(I0{}, I1{}, bfB);
    barrier_raw();
    ldA(1, 1);
    if (s3) stB(t3, 0, 1);
    barrier_raw(); waitlgkm0(); sched0();
    mmaQ(I1{}, I1{}, bfB);
    barrier_raw();
    if (s3) stB(t3, 1, 1);
    if (last) waitvm<0>(); else waitvm<4>();
    barrier_raw();
    mmaQ(I1{}, I0{}, bfA);
    barrier_raw();
  }

  float bv[4];
#pragma unroll
  for (int fn = 0; fn < 4; ++fn)
    bv[fn] = (EPI & 1) ? bias[n0 + wn + fn * 16 + lo] : 0.f;
#pragma unroll
  for (int fm = 0; fm < 8; ++fm)
#pragma unroll
    for (int fn = 0; fn < 4; ++fn) {
      const int col = n0 + wn + fn * 16 + lo;
#pragma unroll
      for (int r = 0; r < 4; ++r) {
        const int row = m0 + wm + fm * 16 + hi * 4 + r;
        float v = acc[fm][fn][r] + bv[fn];
        if (EPI & 4) v = fmaxf(v, 0.f);
        Cp[(size_t)row * N + col] = (ushort_t)f2b(v);
      }
    }
}

// --------------------------- fused QKV ------------------------------------
__global__ __launch_bounds__(256)
void qkv_kernel(const ushort_t* __restrict__ A, const ushort_t* __restrict__ Wq,
                const ushort_t* __restrict__ Wk, const ushort_t* __restrict__ Wv,
                ushort_t* __restrict__ q, ushort_t* __restrict__ k,
                ushort_t* __restrict__ v) {
  __shared__ __align__(16) ushort_t As[128 * 64];
  __shared__ __align__(16) ushort_t Ws[3][64 * 64];
  const int tid = threadIdx.x;
  const int lane = tid & 63, lo = lane & 15, hi = lane >> 4, w = tid >> 6;
  const int m0 = blockIdx.x * 128;
  const int wm = (w >> 1) * 64, wn = (w & 1) * 32;

#pragma unroll
  for (int i = 0; i < 4; ++i) {
    const int c = i * 256 + tid;
    const int r = c >> 3, sg = (c & 7) ^ (r & 7);
    gl16(A + (size_t)(m0 + r) * 64 + sg * 8, As + c * 8);
  }
#pragma unroll
  for (int o = 0; o < 3; ++o) {
    const ushort_t* wb = (o == 0) ? Wq : (o == 1) ? Wk : Wv;
#pragma unroll
    for (int i = 0; i < 2; ++i) {
      const int c = i * 256 + tid;
      const int r = c >> 3, sg = (c & 7) ^ (r & 7);
      gl16(wb + (size_t)r * 64 + sg * 8, Ws[o] + c * 8);
    }
  }
  __syncthreads();

#pragma unroll
  for (int o = 0; o < 3; ++o) {
    ushort_t* ob = (o == 0) ? q : (o == 1) ? k : v;
    const float sc = (o == 0) ? QSCALE : 1.0f;
    f32x4 acc[4][2] = {};
#pragma unroll
    for (int ks = 0; ks < 2; ++ks) {
      short8 af[4], bf[2];
#pragma unroll
      for (int fm = 0; fm < 4; ++fm) {
        const int row = wm + fm * 16 + lo;
        af[fm] = *(const short8*)
            &As[row * 64 + (((ks * 4 + hi) ^ (row & 7)) << 3)];
      }
#pragma unroll
      for (int fn = 0; fn < 2; ++fn) {
        const int row = wn + fn * 16 + lo;
        bf[fn] = *(const short8*)
            &Ws[o][row * 64 + (((ks * 4 + hi) ^ (row & 7)) << 3)];
      }
#pragma unroll
      for (int fm = 0; fm < 4; ++fm)
#pragma unroll
        for (int fn = 0; fn < 2; ++fn)
          acc[fm][fn] = mfma16(af[fm], bf[fn], acc[fm][fn]);
    }
#pragma unroll
    for (int fm = 0; fm < 4; ++fm)
#pragma unroll
      for (int fn = 0; fn < 2; ++fn) {
        const int col = wn + fn * 16 + lo;
#pragma unroll
        for (int r = 0; r < 4; ++r) {
          const int row = m0 + wm + fm * 16 + hi * 4 + r;
          size_t idx;
          if (o == 2) {
            idx = (size_t)row * 64 + col;  // [B,S,H*64]
          } else {
            idx = (size_t)((row >> 15) * 16 + (row & 15)) * 131072 +
                  (size_t)((row >> 4) & 2047) * 64 + col;
          }
          ob[idx] = (ushort_t)f2b(acc[fm][fn][r] * sc);
        }
      }
  }
}

// --------------------------- V transpose (bf16) -----------------------------
__global__ __launch_bounds__(256)
void vtrans(const ushort_t* __restrict__ V, ushort_t* __restrict__ VT) {
  __shared__ ushort_t T[64][65];
  const int tid = threadIdx.x;
  const int s0 = blockIdx.x * 64, hd0 = blockIdx.y * 64, b = blockIdx.z;
  const ushort_t* src = V + (size_t)b * 2097152;
  ushort_t* dst = VT + (size_t)b * 2097152;
#pragma unroll
  for (int i = 0; i < 2; ++i) {
    int c = tid + i * 256;
    int s = c >> 3, kg = c & 7;
    short8 hv = *(const short8*)(src + (size_t)(s0 + s) * 1024 + hd0 + kg * 8);
#pragma unroll
    for (int j = 0; j < 8; ++j) T[s][kg * 8 + j] = (ushort_t)hv[j];
  }
  __syncthreads();
#pragma unroll
  for (int i = 0; i < 2; ++i) {
    int c = tid + i * 256;
    int hd = c >> 3, sg = c & 7;
    short8 o;
#pragma unroll
    for (int j = 0; j < 8; ++j) o[j] = (short)T[sg * 8 + j][hd];
    *(short8*)(dst + (size_t)(hd0 + hd) * 2048 + s0 + sg * 8) = o;
  }
}

// ------ attention split-KV: 32 q-rows/wave, z halves the key range ---------
// Qh,Kh head-major [B,H,S,64] bf16 (Q pre-scaled QSCALE); VT [B,H,64,S] bf16.
// Outputs UNNORMALIZED O partial (bf16, [B,S,H*64]) + per-row lsum.
// grid (16, 32, 2), 256 thr, wave = 32 q rows.
__global__ __launch_bounds__(256)
void attn5(const ushort_t* __restrict__ Qh, const ushort_t* __restrict__ Kh,
           const ushort_t* __restrict__ VT, ushort_t* __restrict__ O0,
           ushort_t* __restrict__ O1, float* __restrict__ L0,
           float* __restrict__ L1) {
  __shared__ __align__(16) ushort_t Kbuf[2][64 * 64];
  __shared__ __align__(16) ushort_t Vbuf[2][64 * 64];
  __shared__ __align__(16) ushort_t Pbuf[4][16 * 40];  // merged (a then b)
  const int tid = threadIdx.x, w = tid >> 6, lane = tid & 63;
  const int lo = lane & 15, hi = lane >> 4;
  const int z = blockIdx.z;
  ushort_t* O = z ? O1 : O0;
  float* L = z ? L1 : L0;
  const int ktb = z * 16;  // this block handles K-tiles [ktb, ktb+16)
  // XCD bh-chunking on (x,y)
  const int hid = blockIdx.y * 16 + blockIdx.x;       // 0..511
  const int logical = (hid & 7) * 64 + (hid >> 3);    // bijective
  const int bh = logical >> 4, qt = logical & 15;
  const int b = bh >> 4, h = bh & 15;
  const size_t hq = (size_t)bh * 131072;
  const size_t vth = (size_t)b * 2097152 + (size_t)h * 131072;
  const size_t oh = (size_t)b * 2097152 + (size_t)h * 64;
  const int qrow = qt * 128 + w * 32;
  ushort_t* Pw = Pbuf[w];

  const ushort_t* qpa = Qh + hq + (size_t)(qrow + lo) * 64 + hi * 8;
  const short8 qf0a = *(const short8*)qpa;
  const short8 qf1a = *(const short8*)(qpa + 32);
  const short8 qf0b = *(const short8*)(qpa + 1024);
  const short8 qf1b = *(const short8*)(qpa + 1024 + 32);

  const int c0 = tid, c1 = 256 + tid;
  const int r0 = c0 >> 3, s0 = ((c0 & 7) ^ (r0 & 7)) << 3;
  const int r1 = c1 >> 3, s1 = ((c1 & 7) ^ (r1 & 7)) << 3;
  const ushort_t* kg0 = Kh + hq + (size_t)r0 * 64 + s0;
  const ushort_t* kg1 = Kh + hq + (size_t)r1 * 64 + s1;
  const ushort_t* vg0 = VT + vth + (size_t)r0 * 2048 + s0;
  const ushort_t* vg1 = VT + vth + (size_t)r1 * 2048 + s1;

  auto stage = [&](int kt, int buf) {
    const int kg = ktb + kt;
    gl16(kg0 + (size_t)kg * 4096, &Kbuf[buf][c0 * 8]);
    gl16(kg1 + (size_t)kg * 4096, &Kbuf[buf][c1 * 8]);
    gl16(vg0 + kg * 64, &Vbuf[buf][c0 * 8]);
    gl16(vg1 + kg * 64, &Vbuf[buf][c1 * 8]);
  };

  f32x4 acca[4] = {}, accb[4] = {};
  f32x4 la = {}, lb = {};
  const int sw = lo & 7;
  const int ko0 = (hi ^ sw) << 3, ko1 = ((4 + hi) ^ sw) << 3;

  auto body = [&](const ushort_t* Kc, const ushort_t* Vc) {
    f32x4 sa[4], sb[4];
#pragma unroll
    for (int fm = 0; fm < 4; ++fm) {
      const int rb = (fm * 16 + lo) * 64;
      short8 k0 = *(const short8*)&Kc[rb + ko0];
      short8 k1 = *(const short8*)&Kc[rb + ko1];
      f32x4 ta = {};
      ta = mfma16(k0, qf0a, ta);
      ta = mfma16(k1, qf1a, ta);
      sa[fm] = ta;
      f32x4 tb = {};
      tb = mfma16(k0, qf0b, tb);
      tb = mfma16(k1, qf1b, tb);
      sb[fm] = tb;
    }
    short8 vf[4][2];
#pragma unroll
    for (int fn = 0; fn < 4; ++fn) {
      const int rb = (fn * 16 + lo) * 64;
      vf[fn][0] = *(const short8*)&Vc[rb + ko0];
      vf[fn][1] = *(const short8*)&Vc[rb + ko1];
    }
    // half a: exp -> P (merged buffer) -> PV
#pragma unroll
    for (int fm = 0; fm < 4; ++fm) {
      f32x4 p;
      p[0] = EXPFN(sa[fm][0]); p[1] = EXPFN(sa[fm][1]);
      p[2] = EXPFN(sa[fm][2]); p[3] = EXPFN(sa[fm][3]);
      la += p;
      uint2 pw;
      pw.x = pkc(p[0], p[1]); pw.y = pkc(p[2], p[3]);
      *(uint2*)&Pw[lo * 40 + fm * 16 + hi * 4] = pw;
    }
    short8 pa0 = *(const short8*)&Pw[lo * 40 + hi * 8];
    short8 pa1 = *(const short8*)&Pw[lo * 40 + 32 + hi * 8];
#pragma unroll
    for (int fn = 0; fn < 4; ++fn) {
      acca[fn] = mfma16(vf[fn][0], pa0, acca[fn]);
      acca[fn] = mfma16(vf[fn][1], pa1, acca[fn]);
    }
    // half b: reuse the same P region (per-wave, DS-pipe in order)
#pragma unroll
    for (int fm = 0; fm < 4; ++fm) {
      f32x4 r;
      r[0] = EXPFN(sb[fm][0]); r[1] = EXPFN(sb[fm][1]);
      r[2] = EXPFN(sb[fm][2]); r[3] = EXPFN(sb[fm][3]);
      lb += r;
      uint2 rw;
      rw.x = pkc(r[0], r[1]); rw.y = pkc(r[2], r[3]);
      *(uint2*)&Pw[lo * 40 + fm * 16 + hi * 4] = rw;
    }
    short8 pb0 = *(const short8*)&Pw[lo * 40 + hi * 8];
    short8 pb1 = *(const short8*)&Pw[lo * 40 + 32 + hi * 8];
#pragma unroll
    for (int fn = 0; fn < 4; ++fn) {
      accb[fn] = mfma16(vf[fn][0], pb0, accb[fn]);
      accb[fn] = mfma16(vf[fn][1], pb1, accb[fn]);
    }
  };

  stage(0, 0);
  __syncthreads();
  for (int kt2 = 0; kt2 < 8; ++kt2) {
    stage(2 * kt2 + 1, 1);
    body(Kbuf[0], Vbuf[0]);
    __syncthreads();
    if (kt2 < 7) stage(2 * kt2 + 2, 0);
    body(Kbuf[1], Vbuf[1]);
    __syncthreads();
  }

  float lsa = (la[0] + la[1]) + (la[2] + la[3]);
  lsa += __shfl_xor(lsa, 16);
  lsa += __shfl_xor(lsa, 32);
  float lsb = (lb[0] + lb[1]) + (lb[2] + lb[3]);
  lsb += __shfl_xor(lsb, 16);
  lsb += __shfl_xor(lsb, 32);
  if (hi == 0) {
    L[bh * 2048 + qrow + lo] = lsa;
    L[bh * 2048 + qrow + 16 + lo] = lsb;
  }
  ushort_t* opa = O + oh + (size_t)(qrow + lo) * 1024 + hi * 4;
  ushort_t* opb = opa + 16 * 1024;
#pragma unroll
  for (int fn = 0; fn < 4; ++fn) {
    uint2 oa, ob;
    oa.x = pk2(acca[fn][0], acca[fn][1]);
    oa.y = pk2(acca[fn][2], acca[fn][3]);
    ob.x = pk2(accb[fn][0], accb[fn][1]);
    ob.y = pk2(accb[fn][2], accb[fn][3]);
    *(uint2*)(opa + fn * 16) = oa;
    *(uint2*)(opb + fn * 16) = ob;
  }
}

// ------------- combine: ctx = (O0 + O1) / (L0 + L1), elementwise ------------
__global__ __launch_bounds__(256)
void attn_combine(const ushort_t* __restrict__ O0,
                  const ushort_t* __restrict__ O1,
                  const float* __restrict__ L0, const float* __restrict__ L1,
                  ushort_t* __restrict__ C) {
  const int bs = blockIdx.x;  // b*2048 + s
  const int tid = threadIdx.x;
  const int b = bs >> 11, s = bs & 2047;
  const int h = tid >> 4;
  const size_t base = (size_t)bs * 1024 + tid * 4;
  const int lrow = (b * 16 + h) * 2048 + s;
  const float inv = 1.0f / (L0[lrow] + L1[lrow]);
  uint2 ua = *(const uint2*)(O0 + base);
  uint2 ub = *(const uint2*)(O1 + base);
  uint2 o;
  o.x = pk2((bl(ua.x) + bl(ub.x)) * inv, (bh(ua.x) + bh(ub.x)) * inv);
  o.y = pk2((bl(ua.y) + bl(ub.y)) * inv, (bh(ua.y) + bh(ub.y)) * inv);
  *(uint2*)(C + base) = o;
}

// --------------------------- launcher --------------------------------------
extern "C" void kernel_launch(void* const* d_in, const int* in_sizes, int n_in,
                              void* d_out, int out_size, void* d_ws,
                              size_t ws_size, hipStream_t stream) {
  const float* x    = (const float*)d_in[0];
  const float* Wq   = (const float*)d_in[1];
  const float* Wk   = (const float*)d_in[2];
  const float* Wv   = (const float*)d_in[3];
  const float* Wo   = (const float*)d_in[4];
  const float* bo   = (const float*)d_in[5];
  const float* ln1g = (const float*)d_in[6];
  const float* ln1b = (const float*)d_in[7];
  const float* W1   = (const float*)d_in[8];
  const float* b1   = (const float*)d_in[9];
  const float* W2   = (const float*)d_in[10];
  const float* b2   = (const float*)d_in[11];
  const float* ln2g = (const float*)d_in[12];
  const float* ln2b = (const float*)d_in[13];
  float* out = (float*)d_out;
  char* wsb = (char*)d_ws;

  ushort_t* t0  = (ushort_t*)wsb;                    // 16 MB: 2 bf16 partials
  ushort_t* t0b = t0 + 4194304;                      // z=1 partial
  ushort_t* q   = (ushort_t*)(wsb + (16ull << 20));  // 8 MB each
  ushort_t* k   = (ushort_t*)(wsb + (24ull << 20));
  ushort_t* v   = (ushort_t*)(wsb + (32ull << 20));
  ushort_t* vt  = (ushort_t*)(wsb + (40ull << 20));
  ushort_t* ff  = q;                                 // 32 MB alias (q..vt)
  ushort_t* ctx = (ushort_t*)(wsb + (48ull << 20));  // 8 MB
  ushort_t* n1b = ctx;                               // alias: ctx dead by ln1
  ushort_t* xbf = (ushort_t*)(wsb + (56ull << 20));  // 8 MB
  ushort_t* wqb = (ushort_t*)(wsb + (64ull << 20));  // 3x24KB
  ushort_t* wkb = wqb + 3 * 4096;
  ushort_t* wvb = wkb + 3 * 4096;
  ushort_t* wob = (ushort_t*)(wsb + (65ull << 20));  // 6 MB (3 layers)
  float*    ls0 = (float*)(wsb + (71ull << 20));     // 256 KB lsum z=0
  float*    ls1 = ls0 + 65536;                       // 256 KB lsum z=1
  ushort_t* w1b = (ushort_t*)(wsb + (72ull << 20));  // 24 MB
  ushort_t* w2b = (ushort_t*)(wsb + (96ull << 20));  // 24 MB

  auto conv = [&](const float* s, ushort_t* d, long n) {
    int n8 = (int)(n / 8);
    int g = (n8 + 255) / 256;
    if (g > 2048) g = 2048;
    conv_bf16<<<g, 256, 0, stream>>>(s, d, n8);
  };
  conv(x, xbf, 4194304);
  conv(Wq, wqb, 3 * 4096);
  conv(Wk, wkb, 3 * 4096);
  conv(Wv, wvb, 3 * 4096);
  conv(Wo, wob, 3ll * 1048576);
  conv(W1, w1b, 3ll * 4194304);
  conv(W2, w2b, 3ll * 4194304);

  const ushort_t* curb = xbf;
  for (int l = 0; l < 3; ++l) {
    qkv_kernel<<<512, 256, 0, stream>>>(curb, wqb + l * 4096, wkb + l * 4096,
                                        wvb + l * 4096, q, k, v);
    vtrans<<<dim3(32, 16, 2), 256, 0, stream>>>(v, vt);
    // split-KV attention: z=0 -> ctx + ls0, z=1 -> t0 + ls1 (both 8MB bufs)
    attn5<<<dim3(16, 32, 2), 256, 0, stream>>>(q, k, vt, ctx, t0, ls0, ls1);
    attn_combine<<<4096, 256, 0, stream>>>(ctx, t0, ls0, ls1, ctx);
    // Wo partials (bf16): 128x128 tile, split-K=2 (Klen=512)
    gemm_db<128, 128, 2, 2, true, 0, true>
        <<<dim3(8, 32, 2), 256, 0, stream>>>(ctx, wob + (size_t)l * 1048576,
                                             nullptr, t0, 4096, 1024, 512,
                                             1024, 1024);
    // n1 = LN(t0a + t0b + bo + residual[curb])
    ln_fuse<false><<<4096, 256, 0, stream>>>(t0, t0b, bo + l * 1024, curb,
                                             ln1g + l * 1024, ln1b + l * 1024,
                                             n1b, nullptr);
    // ff = relu(n1 @ W1^T + b1): 8-phase 256^2, 8 waves
    gemm_8p<5, true><<<dim3(16, 16), 512, 0, stream>>>(
        n1b, w1b + (size_t)l * 4194304, b1 + l * 4096, ff, 4096, 4096, 1024,
        1024, 1024);
    // FF2 partials (bf16): 128x128 tile, split-K=2 (Klen=2048)
    gemm_db<128, 128, 2, 2, true, 0, true>
        <<<dim3(8, 32, 2), 256, 0, stream>>>(ff, w2b + (size_t)l * 4194304,
                                             nullptr, t0, 4096, 1024, 2048,
                                             4096, 4096);
    // out = LN(t0a + t0b + b2 + residual[n1b]); fp32 out only on last layer
    if (l == 2)
      ln_fuse<true><<<4096, 256, 0, stream>>>(t0, t0b, b2 + l * 1024, n1b,
                                              ln2g + l * 1024, ln2b + l * 1024,
                                              xbf, out);
    else
      ln_fuse<false><<<4096, 256, 0, stream>>>(t0, t0b, b2 + l * 1024, n1b,
                                               ln2g + l * 1024, ln2b + l * 1024,
                                               xbf, nullptr);
    curb = xbf;
  }
}

// Round 15
// 522.533 us; speedup vs baseline: 1.0420x; 1.0420x over previous
//
#include <hip/hip_runtime.h>
#include <hip/hip_bf16.h>
#include <math.h>

// ---------------------------------------------------------------------------
// TransformerEncoder L=3,B=2,S=2048,D=1024,H=16,Dh=64,DF=4096.
// Round 15: revert split-KV (r13 structure); attn KVBLK=128 (half the
// barriers/stage calls per key), two sequential 64-key halves reuse the
// per-wave P buffer; V tile [64][128] with 16-group XOR swizzle.
// FF1 8-phase, other GEMMs and glue unchanged from r13.
// ---------------------------------------------------------------------------

#define DEVINL __device__ __forceinline__
typedef unsigned short ushort_t;
using short8 = __attribute__((ext_vector_type(8))) short;
using f32x4  = __attribute__((ext_vector_type(4))) float;

#if defined(__has_builtin)
#if __has_builtin(__builtin_amdgcn_exp2f)
#define EXPFN(x) __builtin_amdgcn_exp2f(x)
#define QSCALE 0.18033688011112042f  // 0.125 * log2(e)
#define HAVE_EXP2 1
#endif
#endif
#ifndef HAVE_EXP2
#define EXPFN(x) __expf(x)
#define QSCALE 0.125f
#endif

DEVINL short f2b(float f) {  // fp32 -> bf16 bits, RNE
  unsigned u = __float_as_uint(f);
  u += 0x7fff + ((u >> 16) & 1);
  return (short)(u >> 16);
}
DEVINL unsigned pk2(float a, float b) {  // two fp32 -> packed bf16x2
  unsigned ua = __float_as_uint(a), ub = __float_as_uint(b);
  ua += 0x7fff + ((ua >> 16) & 1);
  ub += 0x7fff + ((ub >> 16) & 1);
  return (ua >> 16) | (ub & 0xffff0000u);
}
DEVINL unsigned pkc(float a, float b) {  // packed cvt (v_cvt_pk_bf16_f32)
  float2 f; f.x = a; f.y = b;
  __hip_bfloat162 h = __float22bfloat162_rn(f);
  return *reinterpret_cast<unsigned*>(&h);
}
DEVINL float bl(unsigned u) { return __uint_as_float(u << 16); }
DEVINL float bh(unsigned u) { return __uint_as_float(u & 0xffff0000u); }
DEVINL f32x4 mfma16(short8 a, short8 b, f32x4 c) {
  return __builtin_amdgcn_mfma_f32_16x16x32_bf16(a, b, c, 0, 0, 0);
}

typedef __attribute__((address_space(3))) void lds_void;
typedef __attribute__((address_space(1))) void gbl_void;
DEVINL void gl16(const void* g, void* l) {
  __builtin_amdgcn_global_load_lds((const gbl_void*)(unsigned long long)g,
                                   (lds_void*)(unsigned long long)l, 16, 0, 0);
}
template <int N> DEVINL void waitvm() {
  asm volatile("s_waitcnt vmcnt(%0)" ::"n"(N) : "memory");
}
DEVINL void barrier_raw() { __builtin_amdgcn_s_barrier(); }
DEVINL void sched0() { __builtin_amdgcn_sched_barrier(0); }
DEVINL void waitlgkm0() {
  asm volatile("s_waitcnt lgkmcnt(0)" ::: "memory");
}

// --------------------------- fp32 -> bf16 convert ---------------------------
__global__ __launch_bounds__(256)
void conv_bf16(const float* __restrict__ src, ushort_t* __restrict__ dst,
               int n8) {
  int i = blockIdx.x * 256 + threadIdx.x;
  const int stride = gridDim.x * 256;
  for (; i < n8; i += stride) {
    float4 a = ((const float4*)src)[2 * i];
    float4 b = ((const float4*)src)[2 * i + 1];
    uint4 o;
    o.x = pk2(a.x, a.y); o.y = pk2(a.z, a.w);
    o.z = pk2(b.x, b.y); o.w = pk2(b.z, b.w);
    ((uint4*)dst)[i] = o;
  }
}

// -------- LayerNorm of (pa + pb + bias + R) — bf16 in, bf16(+fp32) out ------
DEVINL float block_sum(float v, float* red) {
#pragma unroll
  for (int off = 32; off > 0; off >>= 1) v += __shfl_xor(v, off, 64);
  if ((threadIdx.x & 63) == 0) red[threadIdx.x >> 6] = v;
  __syncthreads();
  float r = red[0] + red[1] + red[2] + red[3];
  __syncthreads();
  return r;
}

template <bool WF>
__global__ __launch_bounds__(256)
void ln_fuse(const ushort_t* __restrict__ pa, const ushort_t* __restrict__ pb,
             const float* __restrict__ bias, const ushort_t* __restrict__ Rb,
             const float* __restrict__ g, const float* __restrict__ b,
             ushort_t* __restrict__ outb, float* __restrict__ outf) {
  __shared__ float red[4];
  const size_t base = (size_t)blockIdx.x * 1024 + threadIdx.x * 4;
  uint2 ua = *(const uint2*)(pa + base);
  uint2 ub = *(const uint2*)(pb + base);
  uint2 ur = *(const uint2*)(Rb + base);
  float4 vbi = *(const float4*)(bias + threadIdx.x * 4);
  float4 v;
  v.x = bl(ua.x) + bl(ub.x) + bl(ur.x) + vbi.x;
  v.y = bh(ua.x) + bh(ub.x) + bh(ur.x) + vbi.y;
  v.z = bl(ua.y) + bl(ub.y) + bl(ur.y) + vbi.z;
  v.w = bh(ua.y) + bh(ub.y) + bh(ur.y) + vbi.w;
  float s = block_sum(v.x + v.y + v.z + v.w, red);
  float mean = s * (1.0f / 1024.0f);
  float dx = v.x - mean, dy = v.y - mean, dz = v.z - mean, dw = v.w - mean;
  float sq = block_sum(dx * dx + dy * dy + dz * dz + dw * dw, red);
  float rstd = rsqrtf(sq * (1.0f / 1024.0f) + 1e-5f);
  const float4 gv = *(const float4*)(g + threadIdx.x * 4);
  const float4 bv = *(const float4*)(b + threadIdx.x * 4);
  float4 o;
  o.x = dx * rstd * gv.x + bv.x;
  o.y = dy * rstd * gv.y + bv.y;
  o.z = dz * rstd * gv.z + bv.z;
  o.w = dw * rstd * gv.w + bv.w;
  uint2 p;
  p.x = pk2(o.x, o.y); p.y = pk2(o.z, o.w);
  *(uint2*)(outb + base) = p;
  if (WF) *(float4*)(outf + base) = o;
}

// ------------------ MFMA GEMM (dbuf + counted vmcnt + raw barriers) ---------
// C[M,N] = A[M,K] @ W[N,K]^T (+bias)(+relu). split-K via blockIdx.z writes
// bf16 partials at offset z*M*N (OBF). EPI: 1=bias 4=relu.
template <int BM, int BN, int WR, int WC, bool OBF, int EPI, bool SWZ>
__global__ __launch_bounds__(WR * WC * 64)
void gemm_db(const ushort_t* __restrict__ A, const ushort_t* __restrict__ W,
             const float* __restrict__ bias, void* __restrict__ Cp, int M,
             int N, int Klen, int lda, int ldw) {
  constexpr int THREADS = WR * WC * 64;
  constexpr int FM = BM / WR / 16;
  constexpr int FN = BN / WC / 16;
  constexpr int CA = BM * 8 / THREADS;
  constexpr int CB = BN * 8 / THREADS;
  constexpr int L = CA + CB;
  __shared__ __align__(16) ushort_t As[2][BM * 64];
  __shared__ __align__(16) ushort_t Bs[2][BN * 64];
  const int tid = threadIdx.x;
  const int lane = tid & 63, lo = lane & 15, hi = lane >> 4, w = tid >> 6;
  int bx = blockIdx.x, by = blockIdx.y;
  if (SWZ) {
    int id = by * gridDim.x + bx;
    const int cpx = (gridDim.x * gridDim.y) >> 3;
    id = (id & 7) * cpx + (id >> 3);
    bx = id % gridDim.x;
    by = id / gridDim.x;
  }
  const int m0 = by * BM, n0 = bx * BN;
  const int wm = (w / WC) * (BM / WR), wn = (w % WC) * (BN / WC);
  const int kbase = blockIdx.z * Klen;

  auto stage = [&](int t, int buf) {
    const int k0 = kbase + t * 64;
#pragma unroll
    for (int i = 0; i < CA; ++i) {
      const int c = i * THREADS + tid;
      const int r = c >> 3, sg = (c & 7) ^ (r & 7);
      gl16(A + (size_t)(m0 + r) * lda + k0 + sg * 8, &As[buf][c * 8]);
    }
#pragma unroll
    for (int i = 0; i < CB; ++i) {
      const int c = i * THREADS + tid;
      const int r = c >> 3, sg = (c & 7) ^ (r & 7);
      gl16(W + (size_t)(n0 + r) * ldw + k0 + sg * 8, &Bs[buf][c * 8]);
    }
  };

  f32x4 acc[FM][FN] = {};
  auto compute = [&](int cur) {
#pragma unroll
    for (int ks = 0; ks < 2; ++ks) {
      short8 af[FM], bf_[FN];
#pragma unroll
      for (int fm = 0; fm < FM; ++fm) {
        const int row = wm + fm * 16 + lo;
        af[fm] = *(const short8*)
            &As[cur][row * 64 + (((ks * 4 + hi) ^ (row & 7)) << 3)];
      }
#pragma unroll
      for (int fn = 0; fn < FN; ++fn) {
        const int row = wn + fn * 16 + lo;
        bf_[fn] = *(const short8*)
            &Bs[cur][row * 64 + (((ks * 4 + hi) ^ (row & 7)) << 3)];
      }
#pragma unroll
      for (int fm = 0; fm < FM; ++fm)
#pragma unroll
        for (int fn = 0; fn < FN; ++fn)
          acc[fm][fn] = mfma16(af[fm], bf_[fn], acc[fm][fn]);
    }
  };

  const int nt = Klen / 64;
  stage(0, 0);
  for (int t = 0; t < nt - 1; ++t) {
    const int cur = t & 1;
    stage(t + 1, cur ^ 1);   // loads stay in flight across both barriers
    waitvm<L>();             // own stage(t) complete (oldest-first retire)
    barrier_raw(); sched0(); // all waves: tile t resident
    compute(cur);
    barrier_raw(); sched0(); // all waves done reading buf cur before restage
  }
  waitvm<0>();
  barrier_raw(); sched0();
  compute((nt - 1) & 1);

  float bv[FN];
#pragma unroll
  for (int fn = 0; fn < FN; ++fn)
    bv[fn] = (EPI & 1) ? bias[n0 + wn + fn * 16 + lo] : 0.f;
#pragma unroll
  for (int fm = 0; fm < FM; ++fm)
#pragma unroll
    for (int fn = 0; fn < FN; ++fn) {
      const int col = n0 + wn + fn * 16 + lo;
#pragma unroll
      for (int r = 0; r < 4; ++r) {
        const int row = m0 + wm + fm * 16 + hi * 4 + r;
        float v = acc[fm][fn][r] + bv[fn];
        if (EPI & 4) v = fmaxf(v, 0.f);
        if (OBF) {
          ushort_t* Cb = (ushort_t*)Cp + (size_t)blockIdx.z * M * N;
          Cb[(size_t)row * N + col] = (ushort_t)f2b(v);
        } else {
          float* Cf = (float*)Cp + (size_t)blockIdx.z * M * N;
          Cf[(size_t)row * N + col] = v;
        }
      }
    }
}

// ---------------- 8-phase 256^2 GEMM (T2+T3+T4+T5, m201 template) -----------
template <int EPI, bool SWZ>
__global__ __launch_bounds__(512, 2)
void gemm_8p(const ushort_t* __restrict__ A, const ushort_t* __restrict__ W,
             const float* __restrict__ bias, ushort_t* __restrict__ Cp, int M,
             int N, int K, int lda, int ldw) {
  __shared__ __align__(16) ushort_t As[2][256 * 64];
  __shared__ __align__(16) ushort_t Bs[2][256 * 64];
  const int tid = threadIdx.x;
  const int lane = tid & 63, lo = lane & 15, hi = lane >> 4, w = tid >> 6;
  const int wr = w >> 2, wc = w & 3;
  int bx = blockIdx.x, by = blockIdx.y;
  if (SWZ) {
    int id = by * gridDim.x + bx;
    const int cpx = (gridDim.x * gridDim.y) >> 3;
    id = (id & 7) * cpx + (id >> 3);
    bx = id % gridDim.x;
    by = id / gridDim.x;
  }
  const int m0 = by * 256, n0 = bx * 256;
  const int wm = wr * 128, wn = wc * 64;

  const int c0 = tid, c1 = 512 + tid;
  const int r0 = c0 >> 3, g0 = ((c0 & 7) ^ (r0 & 7)) << 3;
  const int r1 = c1 >> 3, g1 = ((c1 & 7) ^ (r1 & 7)) << 3;

  auto stA = [&](int tile, int half, int buf) {
    const ushort_t* s = A + (size_t)(m0 + half * 128) * lda + tile * 64;
    ushort_t* d = &As[buf][half * 128 * 64];
    gl16(s + (size_t)r0 * lda + g0, d + c0 * 8);
    gl16(s + (size_t)r1 * lda + g1, d + c1 * 8);
  };
  auto stB = [&](int tile, int half, int buf) {
    const ushort_t* s = W + (size_t)(n0 + half * 128) * ldw + tile * 64;
    ushort_t* d = &Bs[buf][half * 128 * 64];
    gl16(s + (size_t)r0 * ldw + g0, d + c0 * 8);
    gl16(s + (size_t)r1 * ldw + g1, d + c1 * 8);
  };

  f32x4 acc[8][4] = {};
  short8 af[2][4], bfA[2][2], bfB[2][2];

  auto ldA = [&](int buf, int qr) {
#pragma unroll
    for (int ks = 0; ks < 2; ++ks)
#pragma unroll
      for (int fm = 0; fm < 4; ++fm) {
        const int row = wm + qr * 64 + fm * 16 + lo;
        af[ks][fm] = *(const short8*)
            &As[buf][row * 64 + (((ks * 4 + hi) ^ (row & 7)) << 3)];
      }
  };
  auto ldB = [&](int buf, int qc, short8 (&bf)[2][2]) {
#pragma unroll
    for (int ks = 0; ks < 2; ++ks)
#pragma unroll
      for (int fn = 0; fn < 2; ++fn) {
        const int row = wn + qc * 32 + fn * 16 + lo;
        bf[ks][fn] = *(const short8*)
            &Bs[buf][row * 64 + (((ks * 4 + hi) ^ (row & 7)) << 3)];
      }
  };
  auto mmaQ = [&](auto qr, auto qc, short8 (&bf)[2][2]) {
    constexpr int QR = decltype(qr)::value, QC = decltype(qc)::value;
    __builtin_amdgcn_s_setprio(1);
#pragma unroll
    for (int ks = 0; ks < 2; ++ks)
#pragma unroll
      for (int fm = 0; fm < 4; ++fm)
#pragma unroll
        for (int fn = 0; fn < 2; ++fn)
          acc[QR * 4 + fm][QC * 2 + fn] = mfma16(
              af[ks][fm], bf[ks][fn], acc[QR * 4 + fm][QC * 2 + fn]);
    __builtin_amdgcn_s_setprio(0);
  };
  using I0 = std::integral_constant<int, 0>;
  using I1 = std::integral_constant<int, 1>;

  const int nt = K / 64;
  const int ni = nt / 2;

  stA(0, 0, 0); stA(0, 1, 0); stB(0, 0, 0); stB(0, 1, 0);
  stB(1, 0, 1); stB(1, 1, 1);
  waitvm<4>();
  barrier_raw();

  for (int j = 0; j < ni; ++j) {
    const int t1 = 2 * j + 1, t2 = 2 * j + 2, t3 = 2 * j + 3;
    const bool s2 = t2 < nt, s3 = t3 < nt;
    const bool last = (j == ni - 1);
    ldA(0, 0); ldB(0, 0, bfA);
    stA(t1, 0, 1);
    barrier_raw(); waitlgkm0(); sched0();
    mmaQ(I0{}, I0{}, bfA);
    barrier_raw();
    ldB(0, 1, bfB);
    stA(t1, 1, 1);
    barrier_raw(); waitlgkm0(); sched0();
    mmaQ(I0{}, I1{}, bfB);
    barrier_raw();
    ldA(0, 1);
    if (s2) stB(t2, 0, 0);
    barrier_raw(); waitlgkm0(); sched0();
    mmaQ(I1{}, I1{}, bfB);
    barrier_raw();
    if (s2) stB(t2, 1, 0);
    if (last) waitvm<0>(); else waitvm<4>();
    barrier_raw();
    mmaQ(I1{}, I0{}, bfA);
    barrier_raw();
    ldA(1, 0); ldB(1, 0, bfA);
    if (s2) stA(t2, 0, 0);
    barrier_raw(); waitlgkm0(); sched0();
    mmaQ(I0{}, I0{}, bfA);
    barrier_raw();
    ldB(1, 1, bfB);
    if (s2) stA(t2, 1, 0);
    barrier_raw(); waitlgkm0(); sched0();
    mmaQ(I0{}, I1{}, bfB);
    barrier_raw();
    ldA(1, 1);
    if (s3) stB(t3, 0, 1);
    barrier_raw(); waitlgkm0(); sched0();
    mmaQ(I1{}, I1{}, bfB);
    barrier_raw();
    if (s3) stB(t3, 1, 1);
    if (last) waitvm<0>(); else waitvm<4>();
    barrier_raw();
    mmaQ(I1{}, I0{}, bfA);
    barrier_raw();
  }

  float bv[4];
#pragma unroll
  for (int fn = 0; fn < 4; ++fn)
    bv[fn] = (EPI & 1) ? bias[n0 + wn + fn * 16 + lo] : 0.f;
#pragma unroll
  for (int fm = 0; fm < 8; ++fm)
#pragma unroll
    for (int fn = 0; fn < 4; ++fn) {
      const int col = n0 + wn + fn * 16 + lo;
#pragma unroll
      for (int r = 0; r < 4; ++r) {
        const int row = m0 + wm + fm * 16 + hi * 4 + r;
        float v = acc[fm][fn][r] + bv[fn];
        if (EPI & 4) v = fmaxf(v, 0.f);
        Cp[(size_t)row * N + col] = (ushort_t)f2b(v);
      }
    }
}

// --------------------------- fused QKV ------------------------------------
__global__ __launch_bounds__(256)
void qkv_kernel(const ushort_t* __restrict__ A, const ushort_t* __restrict__ Wq,
                const ushort_t* __restrict__ Wk, const ushort_t* __restrict__ Wv,
                ushort_t* __restrict__ q, ushort_t* __restrict__ k,
                ushort_t* __restrict__ v) {
  __shared__ __align__(16) ushort_t As[128 * 64];
  __shared__ __align__(16) ushort_t Ws[3][64 * 64];
  const int tid = threadIdx.x;
  const int lane = tid & 63, lo = lane & 15, hi = lane >> 4, w = tid >> 6;
  const int m0 = blockIdx.x * 128;
  const int wm = (w >> 1) * 64, wn = (w & 1) * 32;

#pragma unroll
  for (int i = 0; i < 4; ++i) {
    const int c = i * 256 + tid;
    const int r = c >> 3, sg = (c & 7) ^ (r & 7);
    gl16(A + (size_t)(m0 + r) * 64 + sg * 8, As + c * 8);
  }
#pragma unroll
  for (int o = 0; o < 3; ++o) {
    const ushort_t* wb = (o == 0) ? Wq : (o == 1) ? Wk : Wv;
#pragma unroll
    for (int i = 0; i < 2; ++i) {
      const int c = i * 256 + tid;
      const int r = c >> 3, sg = (c & 7) ^ (r & 7);
      gl16(wb + (size_t)r * 64 + sg * 8, Ws[o] + c * 8);
    }
  }
  __syncthreads();

#pragma unroll
  for (int o = 0; o < 3; ++o) {
    ushort_t* ob = (o == 0) ? q : (o == 1) ? k : v;
    const float sc = (o == 0) ? QSCALE : 1.0f;
    f32x4 acc[4][2] = {};
#pragma unroll
    for (int ks = 0; ks < 2; ++ks) {
      short8 af[4], bf[2];
#pragma unroll
      for (int fm = 0; fm < 4; ++fm) {
        const int row = wm + fm * 16 + lo;
        af[fm] = *(const short8*)
            &As[row * 64 + (((ks * 4 + hi) ^ (row & 7)) << 3)];
      }
#pragma unroll
      for (int fn = 0; fn < 2; ++fn) {
        const int row = wn + fn * 16 + lo;
        bf[fn] = *(const short8*)
            &Ws[o][row * 64 + (((ks * 4 + hi) ^ (row & 7)) << 3)];
      }
#pragma unroll
      for (int fm = 0; fm < 4; ++fm)
#pragma unroll
        for (int fn = 0; fn < 2; ++fn)
          acc[fm][fn] = mfma16(af[fm], bf[fn], acc[fm][fn]);
    }
#pragma unroll
    for (int fm = 0; fm < 4; ++fm)
#pragma unroll
      for (int fn = 0; fn < 2; ++fn) {
        const int col = wn + fn * 16 + lo;
#pragma unroll
        for (int r = 0; r < 4; ++r) {
          const int row = m0 + wm + fm * 16 + hi * 4 + r;
          size_t idx;
          if (o == 2) {
            idx = (size_t)row * 64 + col;  // [B,S,H*64]
          } else {
            idx = (size_t)((row >> 15) * 16 + (row & 15)) * 131072 +
                  (size_t)((row >> 4) & 2047) * 64 + col;
          }
          ob[idx] = (ushort_t)f2b(acc[fm][fn][r] * sc);
        }
      }
  }
}

// --------------------------- V transpose (bf16) -----------------------------
__global__ __launch_bounds__(256)
void vtrans(const ushort_t* __restrict__ V, ushort_t* __restrict__ VT) {
  __shared__ ushort_t T[64][65];
  const int tid = threadIdx.x;
  const int s0 = blockIdx.x * 64, hd0 = blockIdx.y * 64, b = blockIdx.z;
  const ushort_t* src = V + (size_t)b * 2097152;
  ushort_t* dst = VT + (size_t)b * 2097152;
#pragma unroll
  for (int i = 0; i < 2; ++i) {
    int c = tid + i * 256;
    int s = c >> 3, kg = c & 7;
    short8 hv = *(const short8*)(src + (size_t)(s0 + s) * 1024 + hd0 + kg * 8);
#pragma unroll
    for (int j = 0; j < 8; ++j) T[s][kg * 8 + j] = (ushort_t)hv[j];
  }
  __syncthreads();
#pragma unroll
  for (int i = 0; i < 2; ++i) {
    int c = tid + i * 256;
    int hd = c >> 3, sg = c & 7;
    short8 o;
#pragma unroll
    for (int j = 0; j < 8; ++j) o[j] = (short)T[sg * 8 + j][hd];
    *(short8*)(dst + (size_t)(hd0 + hd) * 2048 + s0 + sg * 8) = o;
  }
}

// ------ attention: KVBLK=128 tiles, 32 q-rows/wave, two 64-key halves -------
// Qh,Kh head-major [B,H,S,64] bf16 (Q pre-scaled QSCALE); VT [B,H,64,S] bf16;
// O [B,S,H,64] bf16. grid (S/128=16, 32) = 512 blocks, 256 thr.
// K tile [128k][64d] (8-group XOR swz); V tile [64d][128k] (16-group XOR swz).
__global__ __launch_bounds__(256)
void attn6(const ushort_t* __restrict__ Qh, const ushort_t* __restrict__ Kh,
           const ushort_t* __restrict__ VT, ushort_t* __restrict__ O) {
  __shared__ __align__(16) ushort_t Kbuf[2][128 * 64];
  __shared__ __align__(16) ushort_t Vbuf[2][64 * 128];
  __shared__ __align__(16) ushort_t Pbuf[4][2][16 * 40];  // 80B row stride
  const int tid = threadIdx.x, w = tid >> 6, lane = tid & 63;
  const int lo = lane & 15, hi = lane >> 4;
  // XCD bh-chunking (bijective: 512 % 8 == 0)
  const int hid = blockIdx.y * 16 + blockIdx.x;
  const int logical = (hid & 7) * 64 + (hid >> 3);
  const int bh = logical >> 4, qt = logical & 15;
  const int b = bh >> 4, h = bh & 15;
  const size_t hq = (size_t)bh * 131072;
  const size_t vth = (size_t)b * 2097152 + (size_t)h * 131072;
  const size_t oh = (size_t)b * 2097152 + (size_t)h * 64;
  const int qrow = qt * 128 + w * 32;
  ushort_t* Pa = Pbuf[w][0];
  ushort_t* Pb = Pbuf[w][1];

  const ushort_t* qpa = Qh + hq + (size_t)(qrow + lo) * 64 + hi * 8;
  const short8 qf0a = *(const short8*)qpa;
  const short8 qf1a = *(const short8*)(qpa + 32);
  const short8 qf0b = *(const short8*)(qpa + 1024);
  const short8 qf1b = *(const short8*)(qpa + 1024 + 32);

  // staging: K 1024 chunks (r=c>>3 key 0..127, kg=c&7, swz 8-group);
  //          V 1024 chunks (r=c>>4 d 0..63, kg=c&15, swz 16-group)
  auto stage = [&](int kt, int buf) {
#pragma unroll
    for (int i = 0; i < 4; ++i) {
      const int c = i * 256 + tid;
      const int r = c >> 3, sg = (c & 7) ^ (r & 7);
      gl16(Kh + hq + (size_t)(kt * 128 + r) * 64 + sg * 8, &Kbuf[buf][c * 8]);
    }
#pragma unroll
    for (int i = 0; i < 4; ++i) {
      const int c = i * 256 + tid;
      const int r = c >> 4, sg = (c & 15) ^ (r & 15);
      gl16(VT + vth + (size_t)r * 2048 + kt * 128 + sg * 8, &Vbuf[buf][c * 8]);
    }
  };

  f32x4 acca[4] = {}, accb[4] = {};
  f32x4 la = {}, lb = {};
  const int sw = lo & 7;
  const int ko0 = (hi ^ sw) << 3, ko1 = ((4 + hi) ^ sw) << 3;

  // one 64-key half: keys hh*64 .. hh*64+63 of the 128-key tile
  auto half_body = [&](const ushort_t* Kc, const ushort_t* Vc, int hh) {
    const ushort_t* Kb2 = Kc + hh * 64 * 64;
    f32x4 sa[4], sb[4];
#pragma unroll
    for (int fm = 0; fm < 4; ++fm) {
      const int rb = (fm * 16 + lo) * 64;
      short8 k0 = *(const short8*)&Kb2[rb + ko0];
      short8 k1 = *(const short8*)&Kb2[rb + ko1];
      f32x4 ta = {};
      ta = mfma16(k0, qf0a, ta);
      ta = mfma16(k1, qf1a, ta);
      sa[fm] = ta;
      f32x4 tb = {};
      tb = mfma16(k0, qf0b, tb);
      tb = mfma16(k1, qf1b, tb);
      sb[fm] = tb;
    }
    // V frags: row = fn*16+lo (d), key group g = hh*8 + ks*4 + hi, swz ^ lo
    short8 vf[4][2];
#pragma unroll
    for (int fn = 0; fn < 4; ++fn) {
      const int rb = (fn * 16 + lo) * 128;
#pragma unroll
      for (int ks = 0; ks < 2; ++ks)
        vf[fn][ks] =
            *(const short8*)&Vc[rb + (((hh * 8 + ks * 4 + hi) ^ lo) << 3)];
    }
#pragma unroll
    for (int fm = 0; fm < 4; ++fm) {
      f32x4 p;
      p[0] = EXPFN(sa[fm][0]); p[1] = EXPFN(sa[fm][1]);
      p[2] = EXPFN(sa[fm][2]); p[3] = EXPFN(sa[fm][3]);
      la += p;
      uint2 pw;
      pw.x = pkc(p[0], p[1]); pw.y = pkc(p[2], p[3]);
      *(uint2*)&Pa[lo * 40 + fm * 16 + hi * 4] = pw;
      f32x4 r;
      r[0] = EXPFN(sb[fm][0]); r[1] = EXPFN(sb[fm][1]);
      r[2] = EXPFN(sb[fm][2]); r[3] = EXPFN(sb[fm][3]);
      lb += r;
      uint2 rw;
      rw.x = pkc(r[0], r[1]); rw.y = pkc(r[2], r[3]);
      *(uint2*)&Pb[lo * 40 + fm * 16 + hi * 4] = rw;
    }
    short8 pa0 = *(const short8*)&Pa[lo * 40 + hi * 8];
    short8 pa1 = *(const short8*)&Pa[lo * 40 + 32 + hi * 8];
    short8 pb0 = *(const short8*)&Pb[lo * 40 + hi * 8];
    short8 pb1 = *(const short8*)&Pb[lo * 40 + 32 + hi * 8];
#pragma unroll
    for (int fn = 0; fn < 4; ++fn) {
      acca[fn] = mfma16(vf[fn][0], pa0, acca[fn]);
      acca[fn] = mfma16(vf[fn][1], pa1, acca[fn]);
      accb[fn] = mfma16(vf[fn][0], pb0, accb[fn]);
      accb[fn] = mfma16(vf[fn][1], pb1, accb[fn]);
    }
  };
  auto body = [&](const ushort_t* Kc, const ushort_t* Vc) {
    half_body(Kc, Vc, 0);   // P buffers reused across halves: per-wave,
    half_body(Kc, Vc, 1);   // DS pipe is in-order (r14-verified pattern)
  };

  stage(0, 0);
  __syncthreads();  // drain stage(0)
  for (int kt2 = 0; kt2 < 8; ++kt2) {
    stage(2 * kt2 + 1, 1);          // in flight during body(buf0)
    body(Kbuf[0], Vbuf[0]);
    __syncthreads();                // drains stage; body(buf0) done by all
    if (kt2 < 7) stage(2 * kt2 + 2, 0);
    body(Kbuf[1], Vbuf[1]);
    __syncthreads();
  }

  float lsa = (la[0] + la[1]) + (la[2] + la[3]);
  lsa += __shfl_xor(lsa, 16);
  lsa += __shfl_xor(lsa, 32);
  float lsb = (lb[0] + lb[1]) + (lb[2] + lb[3]);
  lsb += __shfl_xor(lsb, 16);
  lsb += __shfl_xor(lsb, 32);
  const float inva = 1.0f / lsa, invb = 1.0f / lsb;
  ushort_t* opa = O + oh + (size_t)(qrow + lo) * 1024 + hi * 4;
  ushort_t* opb = opa + 16 * 1024;
#pragma unroll
  for (int fn = 0; fn < 4; ++fn) {
    uint2 oa, ob;
    oa.x = pk2(acca[fn][0] * inva, acca[fn][1] * inva);
    oa.y = pk2(acca[fn][2] * inva, acca[fn][3] * inva);
    ob.x = pk2(accb[fn][0] * invb, accb[fn][1] * invb);
    ob.y = pk2(accb[fn][2] * invb, accb[fn][3] * invb);
    *(uint2*)(opa + fn * 16) = oa;
    *(uint2*)(opb + fn * 16) = ob;
  }
}

// --------------------------- launcher --------------------------------------
extern "C" void kernel_launch(void* const* d_in, const int* in_sizes, int n_in,
                              void* d_out, int out_size, void* d_ws,
                              size_t ws_size, hipStream_t stream) {
  const float* x    = (const float*)d_in[0];
  const float* Wq   = (const float*)d_in[1];
  const float* Wk   = (const float*)d_in[2];
  const float* Wv   = (const float*)d_in[3];
  const float* Wo   = (const float*)d_in[4];
  const float* bo   = (const float*)d_in[5];
  const float* ln1g = (const float*)d_in[6];
  const float* ln1b = (const float*)d_in[7];
  const float* W1   = (const float*)d_in[8];
  const float* b1   = (const float*)d_in[9];
  const float* W2   = (const float*)d_in[10];
  const float* b2   = (const float*)d_in[11];
  const float* ln2g = (const float*)d_in[12];
  const float* ln2b = (const float*)d_in[13];
  float* out = (float*)d_out;
  char* wsb = (char*)d_ws;

  ushort_t* t0  = (ushort_t*)wsb;                    // 16 MB: 2 bf16 partials
  ushort_t* t0b = t0 + 4194304;                      // z=1 partial
  ushort_t* q   = (ushort_t*)(wsb + (16ull << 20));  // 8 MB each
  ushort_t* k   = (ushort_t*)(wsb + (24ull << 20));
  ushort_t* v   = (ushort_t*)(wsb + (32ull << 20));
  ushort_t* vt  = (ushort_t*)(wsb + (40ull << 20));
  ushort_t* ff  = q;                                 // 32 MB alias (q..vt)
  ushort_t* ctx = (ushort_t*)(wsb + (48ull << 20));  // 8 MB
  ushort_t* n1b = ctx;                               // alias: ctx dead by ln1
  ushort_t* xbf = (ushort_t*)(wsb + (56ull << 20));  // 8 MB
  ushort_t* wqb = (ushort_t*)(wsb + (64ull << 20));  // 3x24KB
  ushort_t* wkb = wqb + 3 * 4096;
  ushort_t* wvb = wkb + 3 * 4096;
  ushort_t* wob = (ushort_t*)(wsb + (65ull << 20));  // 6 MB (3 layers)
  ushort_t* w1b = (ushort_t*)(wsb + (72ull << 20));  // 24 MB
  ushort_t* w2b = (ushort_t*)(wsb + (96ull << 20));  // 24 MB

  auto conv = [&](const float* s, ushort_t* d, long n) {
    int n8 = (int)(n / 8);
    int g = (n8 + 255) / 256;
    if (g > 2048) g = 2048;
    conv_bf16<<<g, 256, 0, stream>>>(s, d, n8);
  };
  conv(x, xbf, 4194304);
  conv(Wq, wqb, 3 * 4096);
  conv(Wk, wkb, 3 * 4096);
  conv(Wv, wvb, 3 * 4096);
  conv(Wo, wob, 3ll * 1048576);
  conv(W1, w1b, 3ll * 4194304);
  conv(W2, w2b, 3ll * 4194304);

  const ushort_t* curb = xbf;
  for (int l = 0; l < 3; ++l) {
    qkv_kernel<<<512, 256, 0, stream>>>(curb, wqb + l * 4096, wkb + l * 4096,
                                        wvb + l * 4096, q, k, v);
    vtrans<<<dim3(32, 16, 2), 256, 0, stream>>>(v, vt);
    attn6<<<dim3(16, 32), 256, 0, stream>>>(q, k, vt, ctx);
    // Wo partials (bf16): 128x128 tile, split-K=2 (Klen=512)
    gemm_db<128, 128, 2, 2, true, 0, true>
        <<<dim3(8, 32, 2), 256, 0, stream>>>(ctx, wob + (size_t)l * 1048576,
                                             nullptr, t0, 4096, 1024, 512,
                                             1024, 1024);
    // n1 = LN(t0a + t0b + bo + residual[curb])
    ln_fuse<false><<<4096, 256, 0, stream>>>(t0, t0b, bo + l * 1024, curb,
                                             ln1g + l * 1024, ln1b + l * 1024,
                                             n1b, nullptr);
    // ff = relu(n1 @ W1^T + b1): 8-phase 256^2, 8 waves
    gemm_8p<5, true><<<dim3(16, 16), 512, 0, stream>>>(
        n1b, w1b + (size_t)l * 4194304, b1 + l * 4096, ff, 4096, 4096, 1024,
        1024, 1024);
    // FF2 partials (bf16): 128x128 tile, split-K=2 (Klen=2048)
    gemm_db<128, 128, 2, 2, true, 0, true>
        <<<dim3(8, 32, 2), 256, 0, stream>>>(ff, w2b + (size_t)l * 4194304,
                                             nullptr, t0, 4096, 1024, 2048,
                                             4096, 4096);
    // out = LN(t0a + t0b + b2 + residual[n1b]); fp32 out only on last layer
    if (l == 2)
      ln_fuse<true><<<4096, 256, 0, stream>>>(t0, t0b, b2 + l * 1024, n1b,
                                              ln2g + l * 1024, ln2b + l * 1024,
                                              xbf, out);
    else
      ln_fuse<false><<<4096, 256, 0, stream>>>(t0, t0b, b2 + l * 1024, n1b,
                                               ln2g + l * 1024, ln2b + l * 1024,
                                               xbf, nullptr);
    curb = xbf;
  }
}